// Round 21
// baseline (133.208 us; speedup 1.0000x reference)
//
#include <hip/hip_runtime.h>
#include <hip/hip_bf16.h>

typedef unsigned short u16;
typedef unsigned int u32;
typedef __bf16 bf16x8 __attribute__((ext_vector_type(8)));
typedef float f32x4 __attribute__((ext_vector_type(4)));

#define NB 2
#define NSEQ 2048
#define NDIM 1024
#define NH 16
#define NDH 64

static __device__ __forceinline__ u16 f2bf(float f) {
  return __builtin_bit_cast(u16, (__bf16)f);   // hw v_cvt RNE
}
static __device__ __forceinline__ float bf2f(u16 u) {
  union { u32 u; float f; } a; a.u = ((u32)u) << 16; return a.f;
}
static __device__ __forceinline__ bf16x8 ldbf8(const u16* p) {
  return *(const bf16x8*)p;
}
static __device__ __forceinline__ f32x4 mfma16(bf16x8 a, bf16x8 b, f32x4 c) {
  return __builtin_amdgcn_mfma_f32_16x16x32_bf16(a, b, c, 0, 0, 0);
}
static __device__ __forceinline__ float fexp2(float x) {
  return __builtin_amdgcn_exp2f(x);            // v_exp_f32: 2^x
}
// async global->LDS, 16B per lane; LDS dest wave-uniform base + lane*16
#define GLDS(g, d) __builtin_amdgcn_global_load_lds(                         \
    (const __attribute__((address_space(1))) void*)(g),                      \
    (__attribute__((address_space(3))) void*)(d), 16, 0, 0)

// ---------- transpose + fp32 -> bf16 : out[c][r] = bf16(in[r][c]) ----------
__global__ __launch_bounds__(256) void k_transpose(const float* __restrict__ in,
                                                   u16* __restrict__ out,
                                                   int R, int C) {
  __shared__ u16 tile[64][65];
  const int r0 = blockIdx.x * 64, c0 = blockIdx.y * 64;
  const int t = threadIdx.x;
  const int tr = t >> 6;      // 0..3
  const int tc = t & 63;
#pragma unroll 4
  for (int p = 0; p < 16; p++) {
    int r = p * 4 + tr;
    tile[r][tc] = f2bf(in[(size_t)(r0 + r) * C + (c0 + tc)]);
  }
  __syncthreads();
#pragma unroll 4
  for (int p = 0; p < 16; p++) {
    int rr = p * 4 + tr;
    out[(size_t)(c0 + rr) * R + (r0 + tc)] = tile[tc][rr];
  }
}

// ---------- RMSNorm (l2norm * sqrt(DIM) * (gamma+1)), fp32 -> bf16 ----------
__global__ __launch_bounds__(256) void k_rmsnorm(const float* __restrict__ x,
                                                 const float* __restrict__ gamma,
                                                 u16* __restrict__ xn) {
  __shared__ float part[4];
  const int row = blockIdx.x;
  const int t = threadIdx.x;
  const float4 v = ((const float4*)(x + (size_t)row * NDIM))[t];
  float ss = v.x * v.x + v.y * v.y + v.z * v.z + v.w * v.w;
#pragma unroll
  for (int off = 1; off < 64; off <<= 1) ss += __shfl_xor(ss, off, 64);
  if ((t & 63) == 0) part[t >> 6] = ss;
  __syncthreads();
  const float tot = part[0] + part[1] + part[2] + part[3];
  const float scale = 32.0f / fmaxf(sqrtf(tot), 1e-12f);  // sqrt(1024)=32
  const float4 g = ((const float4*)gamma)[t];
  u16 o0 = f2bf(v.x * scale * (g.x + 1.0f));
  u16 o1 = f2bf(v.y * scale * (g.y + 1.0f));
  u16 o2 = f2bf(v.z * scale * (g.z + 1.0f));
  u16 o3 = f2bf(v.w * scale * (g.w + 1.0f));
  uint2 pv;
  pv.x = (u32)o0 | ((u32)o1 << 16);
  pv.y = (u32)o2 | ((u32)o3 << 16);
  *(uint2*)(xn + (size_t)row * NDIM + t * 4) = pv;
}

// ---------- GEMM: C[M,N] = A[M,1024] @ BT[N,1024]^T (bf16 in) --------------
// BK=64 conflict-free b128 geometry, 8-chunk XOR swizzle pre-applied at the
// global source (rule #21).
// DB=0: single-buffered, 2 barriers/K-step (round-7/8 proven).
// DB=1: double-buffered, ONE barrier/K-step, prefetch flies over compute.
//   At 64x64 dbuf LDS = 32KB -> 5 blk/CU (occupancy preserved, unlike the
//   round-14/15 dbuf failures at 2 blk/CU).
// EPI 0: write fp32 Of[row*1024 + col]  (out-proj, straight to d_out)
// EPI 1: scatter bf16 -> Q,K as [B,H,N,DH]; V TRANSPOSED as [B,H,DH,NSEQ]
template <int EPI, int BM, int BN, int DB>
__global__ __launch_bounds__(256) void k_gemm_bt(const u16* __restrict__ A,
                                                 const u16* __restrict__ BT,
                                                 float* __restrict__ Of,
                                                 u16* __restrict__ O0,
                                                 u16* __restrict__ O1,
                                                 u16* __restrict__ O2) {
  constexpr int KD = 1024, BK = 64, NT = KD / BK;
  constexpr int MI = BM / 32, NI = BN / 32;   // frags per wave (2x2 grid)
  constexpr int AI = BM / 32, BI = BN / 32;   // staging instrs per wave
  constexpr int NBUF = DB ? 2 : 1;
  __shared__ u16 As[NBUF * BM * BK];
  __shared__ u16 Bs[NBUF * BN * BK];
  const int m0 = blockIdx.x * BM, n0 = blockIdx.y * BN;
  const int t = threadIdx.x;
  const int w = t >> 6, l = t & 63, lo = l & 15, hi = l >> 4;
  const int wr = (w >> 1) * (BM / 2), wc = (w & 1) * (BN / 2);
  const int rl = l >> 3;
  const int sc8 = ((l & 7) ^ rl) * 8;
  const u16* agp[AI];
  u16* asd[AI];
#pragma unroll
  for (int i = 0; i < AI; i++) {
    const int ii = w * AI + i;
    agp[i] = A + (size_t)(m0 + ii * 8 + rl) * KD + sc8;
    asd[i] = (u16*)As + ii * 512;
  }
  const u16* bgp[BI];
  u16* bsd[BI];
#pragma unroll
  for (int i = 0; i < BI; i++) {
    const int ii = w * BI + i;
    bgp[i] = BT + (size_t)(n0 + ii * 8 + rl) * KD + sc8;
    bsd[i] = (u16*)Bs + ii * 512;
  }
  f32x4 acc[MI][NI] = {};

#define GSTAGE(bb, kt_)                                                       \
  {                                                                           \
    _Pragma("unroll")                                                         \
    for (int i_ = 0; i_ < AI; i_++)                                           \
      GLDS(agp[i_] + (kt_) * BK, asd[i_] + (bb) * BM * BK);                   \
    _Pragma("unroll")                                                         \
    for (int i_ = 0; i_ < BI; i_++)                                           \
      GLDS(bgp[i_] + (kt_) * BK, bsd[i_] + (bb) * BN * BK);                   \
  }

  int cur = 0;
  if (DB) GSTAGE(0, 0);
  for (int kt = 0; kt < NT; kt++) {
    if (DB) {
      __syncthreads();                 // buf[cur] staged (vmcnt drained)
      if (kt + 1 < NT) GSTAGE(cur ^ 1, kt + 1);   // lands during compute
    } else {
      __syncthreads();                 // prev tile's reads done
      GSTAGE(0, kt);
      __syncthreads();                 // drains vmcnt -> staged
    }
    const u16* as = (const u16*)As + cur * BM * BK;
    const u16* bs = (const u16*)Bs + cur * BN * BK;
    bf16x8 af[MI][2], bb[NI][2];
#pragma unroll
    for (int i = 0; i < MI; i++) {
      const int Ra = wr + i * 16 + lo, xa = Ra & 7;
      af[i][0] = ldbf8(&as[Ra * 64 + ((hi ^ xa) << 3)]);
      af[i][1] = ldbf8(&as[Ra * 64 + (((4 + hi) ^ xa) << 3)]);
    }
#pragma unroll
    for (int j = 0; j < NI; j++) {
      const int Rb = wc + j * 16 + lo, xb = Rb & 7;
      bb[j][0] = ldbf8(&bs[Rb * 64 + ((hi ^ xb) << 3)]);
      bb[j][1] = ldbf8(&bs[Rb * 64 + (((4 + hi) ^ xb) << 3)]);
    }
#pragma unroll
    for (int i = 0; i < MI; i++)
#pragma unroll
      for (int j = 0; j < NI; j++) {
        acc[i][j] = mfma16(af[i][0], bb[j][0], acc[i][j]);
        acc[i][j] = mfma16(af[i][1], bb[j][1], acc[i][j]);
      }
    if (DB) cur ^= 1;
  }
#undef GSTAGE

#pragma unroll
  for (int i = 0; i < MI; i++) {
#pragma unroll
    for (int j = 0; j < NI; j++) {
      const int gr0 = m0 + wr + i * 16 + hi * 4;
      const int gc = n0 + wc + j * 16 + lo;
#pragma unroll
      for (int r = 0; r < 4; r++) {
        const int row = gr0 + r;
        if (EPI == 0) {
          Of[(size_t)row * 1024 + gc] = acc[i][j][r];   // fp32 output
        } else {
          const u16 bv = f2bf(acc[i][j][r]);
          const int which = gc >> 10, rem = gc & 1023;
          const int h = rem >> 6, dh = rem & 63;
          const int b = row >> 11, ns = row & 2047;
          if (which == 2) {   // V transposed: [B,H,DH,NSEQ]
            O2[(((size_t)b * NH + h) * NDH + dh) * NSEQ + ns] = bv;
          } else {
            const size_t idx = ((((size_t)b * NH + h) * NSEQ) + ns) * NDH + dh;
            (which == 0 ? O0 : O1)[idx] = bv;
          }
        }
      }
    }
  }
}

// ---------- rotary (interleaved pairs) on q (scaled) and k, fused ----------
__global__ __launch_bounds__(256) void k_rotary(u16* __restrict__ qb,
                                                u16* __restrict__ kb,
                                                const float* __restrict__ rot) {
  const int gi = blockIdx.x * 256 + threadIdx.x;   // 8-elem group id
  const int half = gi >> 19;                       // 2^19 groups per tensor
  const int i = gi & ((1 << 19) - 1);
  u16* buf = half ? kb : qb;
  const float scale = half ? 1.0f : 0.125f;        // q * DH^-0.5 folded in
  const int d0 = (i & 7) * 8;
  const int n = (i >> 3) & (NSEQ - 1);
  union { uint4 v; u16 s[8]; } u;
  u.v = *(const uint4*)(buf + (size_t)i * 8);
  float fr[8];
  *(float4*)&fr[0] = *(const float4*)(rot + n * NDH + d0);
  *(float4*)&fr[4] = *(const float4*)(rot + n * NDH + d0 + 4);
  union { uint4 v; u16 s[8]; } o;
#pragma unroll
  for (int p = 0; p < 4; p++) {
    float a = bf2f(u.s[2 * p]), b = bf2f(u.s[2 * p + 1]);
    float s0, c0, s1, c1;
    __sincosf(fr[2 * p], &s0, &c0);
    __sincosf(fr[2 * p + 1], &s1, &c1);
    o.s[2 * p] = f2bf((a * c0 - b * s0) * scale);
    o.s[2 * p + 1] = f2bf((b * c1 + a * s1) * scale);
  }
  *(uint4*)(buf + (size_t)i * 8) = o.v;
}

// ---------- flash attention: softcap, fixed-m softmax (m=0), causal --------
// p = exp(50*tanh(s/50)) via single exp2 + poly (log2e folded into consts).
// QBLK=64, 4-wave blocks: pairs (t,31-t) -> 33 uniform KV-tiles/block;
// grid 512 = 2 blocks/CU = 16 waves/CU. Async dbuf K/V staging via
// global_load_lds, ONE barrier per tile. (round-19 proven)
#define KCH(row, ch) ((((ch) ^ ((row) & 7)) * 8))
__global__ __launch_bounds__(256, 4) void k_attn(const u16* __restrict__ Q,
                                                 const u16* __restrict__ K,
                                                 const u16* __restrict__ Vt,
                                                 u16* __restrict__ O) {
  __shared__ u16 Ks[2][4096];       // [kv][dh] 16B-chunk XOR swizzled
  __shared__ u16 Vs[2][4096];       // [dh][kv] 16B-chunk XOR swizzled
  __shared__ u16 Ps[4][16][64];     // per-wave P [qrow][kv], XOR swizzled
  const int pr = blockIdx.x >> 5;          // 0..15 pair index
  const int bh = blockIdx.x & 31;
  const int b = bh >> 4, h = bh & 15;
  const size_t base = (size_t)bh * (NSEQ * NDH);
  const int t = threadIdx.x;
  const int w = t >> 6, l = t & 63, lo = l & 15, hi = l >> 4;

  const int rl = l >> 3;                  // row-in-chunk 0..7
  const int sc8 = ((l & 7) ^ rl) * 8;     // pre-swizzled chunk offset (elems)
  const size_t vtb = (size_t)bh * NDH * NSEQ;

#define STAGE(bb, kt_)                                                        \
  {                                                                           \
    _Pragma("unroll")                                                         \
    for (int i_ = 0; i_ < 2; i_++) {                                          \
      const int ii = w * 2 + i_;                                              \
      const int R_ = ii * 8 + rl;                                             \
      GLDS(K + base + (size_t)((kt_) * 64 + R_) * NDH + sc8,                  \
           &Ks[bb][ii * 512]);                                                \
      GLDS(Vt + vtb + (size_t)R_ * NSEQ + (kt_) * 64 + sc8,                   \
           &Vs[bb][ii * 512]);                                                \
    }                                                                         \
  }

  int cur = 0;
  STAGE(0, 0);                            // prologue: half0 tile0

#pragma unroll
  for (int half = 0; half < 2; half++) {
    const int qt = half ? (31 - pr) : pr;   // 64-row q tile
    const int q0 = qt * 64;
    bf16x8 aq0, aq1;
    {
      const u16* qp = Q + base + (size_t)(q0 + w * 16 + lo) * NDH;
      aq0 = ldbf8(qp + hi * 8);
      aq1 = ldbf8(qp + 32 + hi * 8);
    }
    f32x4 accO[4] = {};
    float l_part[4] = {0.f, 0.f, 0.f, 0.f};
    const int nkt = qt + 1;
    const int ktd = qt;                  // diagonal tile index
    const int rowg = q0 + w * 16 + hi * 4;

    for (int kt = 0; kt < nkt; kt++) {
      __syncthreads();   // drains vmcnt -> buf[cur] staged; prev reads done
      if (kt + 1 < nkt) {
        STAGE(cur ^ 1, kt + 1);          // flies over this tile's compute
      } else if (half == 0) {
        STAGE(cur ^ 1, 0);               // prefetch half1 tile0
      }

      // S = Q K^T
      const u16* ks = Ks[cur];
      const u16* vs = Vs[cur];
      f32x4 s[4];
#pragma unroll
      for (int nt = 0; nt < 4; nt++) {
        const int kr = nt * 16 + lo;
        f32x4 z = {};
        z = mfma16(aq0, ldbf8(&ks[kr * 64 + KCH(kr, hi)]), z);
        z = mfma16(aq1, ldbf8(&ks[kr * 64 + KCH(kr, 4 + hi)]), z);
        s[nt] = z;
      }
      // softcap+exp fused: p = 2^(v*(log2e - a2*z^2 + a4*z^4)), z=v/50
      const bool diag = (kt == ktd);
#pragma unroll
      for (int nt = 0; nt < 4; nt++) {
        const int col = kt * 64 + nt * 16 + lo;
#pragma unroll
        for (int r = 0; r < 4; r++) {
          const float v = s[nt][r];
          const float u = v * v;
          float p = fexp2(v * fmaf(u, fmaf(u, 3.0777855e-8f,
                                           -1.9235932e-4f), 1.44269504f));
          if (diag && col > rowg + r) p = 0.0f;
          s[nt][r] = p;
          l_part[r] += p;
        }
      }
      // P -> LDS (bf16), transpose C-layout -> A-frag layout (XOR swizzled)
#pragma unroll
      for (int nt = 0; nt < 4; nt++)
#pragma unroll
        for (int r = 0; r < 4; r++) {
          const int row = hi * 4 + r;
          Ps[w][row][KCH(row, 2 * nt + (lo >> 3)) + (lo & 7)] = f2bf(s[nt][r]);
        }

      const bf16x8 ap0 = ldbf8(&Ps[w][lo][KCH(lo, hi)]);
      const bf16x8 ap1 = ldbf8(&Ps[w][lo][KCH(lo, 4 + hi)]);
#pragma unroll
      for (int dt = 0; dt < 4; dt++) {
        const int d = dt * 16 + lo;
        accO[dt] = mfma16(ap0, ldbf8(&vs[d * 64 + KCH(d, hi)]), accO[dt]);
        accO[dt] = mfma16(ap1, ldbf8(&vs[d * 64 + KCH(d, 4 + hi)]), accO[dt]);
      }
      cur ^= 1;
    }
    // epilogue: reduce l across the 16 lo-lanes, normalize, write [B,N,H*DH]
    float lr[4];
#pragma unroll
    for (int r = 0; r < 4; r++) {
      float lv = l_part[r];
      lv += __shfl_xor(lv, 1, 64);
      lv += __shfl_xor(lv, 2, 64);
      lv += __shfl_xor(lv, 4, 64);
      lv += __shfl_xor(lv, 8, 64);
      lr[r] = __builtin_amdgcn_rcpf(lv);
    }
#pragma unroll
    for (int dt = 0; dt < 4; dt++) {
#pragma unroll
      for (int r = 0; r < 4; r++) {
        const int row = rowg + r;
        const float v = accO[dt][r] * lr[r];
        const size_t idx = (((size_t)(b * NSEQ + row)) * NH + h) * NDH + dt * 16 + lo;
        O[idx] = f2bf(v);
      }
    }
  }
#undef STAGE
}

extern "C" void kernel_launch(void* const* d_in, const int* in_sizes, int n_in,
                              void* d_out, int out_size, void* d_ws, size_t ws_size,
                              hipStream_t stream) {
  const float* x     = (const float*)d_in[0];
  // d_in[1] = attn_mask (bool causal tril) -- implemented directly
  const float* rot   = (const float*)d_in[2];
  const float* gamma = (const float*)d_in[3];
  const float* wqkv  = (const float*)d_in[4];
  const float* wout  = (const float*)d_in[5];

  char* ws = (char*)d_ws;
  u16* xn    = (u16*)(ws);                        // 8 MB, reused as attn-out
  u16* wqkvT = (u16*)(ws + (size_t)( 8u << 20));  // 6 MB
  u16* woutT = (u16*)(ws + (size_t)(14u << 20));  // 2 MB
  u16* qb    = (u16*)(ws + (size_t)(16u << 20));  // 8 MB
  u16* kb    = (u16*)(ws + (size_t)(24u << 20));  // 8 MB
  u16* vt    = (u16*)(ws + (size_t)(32u << 20));  // 8 MB  [B,H,DH,NSEQ]
  u16* ob    = xn;                                 // xn dead after QKV GEMM

  k_transpose<<<dim3(16, 48), 256, 0, stream>>>(wqkv, wqkvT, 1024, 3072);
  k_transpose<<<dim3(16, 16), 256, 0, stream>>>(wout, woutT, 1024, 1024);
  k_rmsnorm<<<4096, 256, 0, stream>>>(x, gamma, xn);
  k_gemm_bt<1, 64, 64, 1><<<dim3(64, 48), 256, 0, stream>>>(
      xn, wqkvT, nullptr, qb, kb, vt);                       // dbuf QKV
  k_rotary<<<4096, 256, 0, stream>>>(qb, kb, rot);
  k_attn<<<512, 256, 0, stream>>>(qb, kb, vt, ob);
  k_gemm_bt<0, 64, 64, 0><<<dim3(64, 16), 256, 0, stream>>>(
      ob, woutT, (float*)d_out, nullptr, nullptr, nullptr);  // single out-proj
}

// Round 22
// 122.619 us; speedup vs baseline: 1.0864x; 1.0864x over previous
//
#include <hip/hip_runtime.h>
#include <hip/hip_bf16.h>

typedef unsigned short u16;
typedef unsigned int u32;
typedef __bf16 bf16x8 __attribute__((ext_vector_type(8)));
typedef float f32x4 __attribute__((ext_vector_type(4)));

#define NB 2
#define NSEQ 2048
#define NDIM 1024
#define NH 16
#define NDH 64

static __device__ __forceinline__ u16 f2bf(float f) {
  return __builtin_bit_cast(u16, (__bf16)f);   // hw v_cvt RNE
}
static __device__ __forceinline__ float bf2f(u16 u) {
  union { u32 u; float f; } a; a.u = ((u32)u) << 16; return a.f;
}
static __device__ __forceinline__ bf16x8 ldbf8(const u16* p) {
  return *(const bf16x8*)p;
}
static __device__ __forceinline__ f32x4 mfma16(bf16x8 a, bf16x8 b, f32x4 c) {
  return __builtin_amdgcn_mfma_f32_16x16x32_bf16(a, b, c, 0, 0, 0);
}
static __device__ __forceinline__ float fexp2(float x) {
  return __builtin_amdgcn_exp2f(x);            // v_exp_f32: 2^x
}
// async global->LDS, 16B per lane; LDS dest wave-uniform base + lane*16
#define GLDS(g, d) __builtin_amdgcn_global_load_lds(                         \
    (const __attribute__((address_space(1))) void*)(g),                      \
    (__attribute__((address_space(3))) void*)(d), 16, 0, 0)

// ---------- transpose + fp32 -> bf16 : out[c][r] = bf16(in[r][c]) ----------
__global__ __launch_bounds__(256) void k_transpose(const float* __restrict__ in,
                                                   u16* __restrict__ out,
                                                   int R, int C) {
  __shared__ u16 tile[64][65];
  const int r0 = blockIdx.x * 64, c0 = blockIdx.y * 64;
  const int t = threadIdx.x;
  const int tr = t >> 6;      // 0..3
  const int tc = t & 63;
#pragma unroll 4
  for (int p = 0; p < 16; p++) {
    int r = p * 4 + tr;
    tile[r][tc] = f2bf(in[(size_t)(r0 + r) * C + (c0 + tc)]);
  }
  __syncthreads();
#pragma unroll 4
  for (int p = 0; p < 16; p++) {
    int rr = p * 4 + tr;
    out[(size_t)(c0 + rr) * R + (r0 + tc)] = tile[tc][rr];
  }
}

// ---------- RMSNorm (l2norm * sqrt(DIM) * (gamma+1)), fp32 -> bf16 ----------
__global__ __launch_bounds__(256) void k_rmsnorm(const float* __restrict__ x,
                                                 const float* __restrict__ gamma,
                                                 u16* __restrict__ xn) {
  __shared__ float part[4];
  const int row = blockIdx.x;
  const int t = threadIdx.x;
  const float4 v = ((const float4*)(x + (size_t)row * NDIM))[t];
  float ss = v.x * v.x + v.y * v.y + v.z * v.z + v.w * v.w;
#pragma unroll
  for (int off = 1; off < 64; off <<= 1) ss += __shfl_xor(ss, off, 64);
  if ((t & 63) == 0) part[t >> 6] = ss;
  __syncthreads();
  const float tot = part[0] + part[1] + part[2] + part[3];
  const float scale = 32.0f / fmaxf(sqrtf(tot), 1e-12f);  // sqrt(1024)=32
  const float4 g = ((const float4*)gamma)[t];
  u16 o0 = f2bf(v.x * scale * (g.x + 1.0f));
  u16 o1 = f2bf(v.y * scale * (g.y + 1.0f));
  u16 o2 = f2bf(v.z * scale * (g.z + 1.0f));
  u16 o3 = f2bf(v.w * scale * (g.w + 1.0f));
  uint2 pv;
  pv.x = (u32)o0 | ((u32)o1 << 16);
  pv.y = (u32)o2 | ((u32)o3 << 16);
  *(uint2*)(xn + (size_t)row * NDIM + t * 4) = pv;
}

// ---------- GEMM: C[M,N] = A[M,1024] @ BT[N,1024]^T (bf16 in) --------------
// Single-buffered GLDS staging (proven; dbuf measured null at all occupancy
// regimes), BK=64 conflict-free b128 geometry, 8-chunk XOR swizzle
// pre-applied at the global source (rule #21).
// QKV 64x128 (24KB -> 6 blk/CU), out-proj 64x64 (16KB -> 8 blk/CU).
// EPI 0: write fp32 Of[row*1024 + col]  (out-proj, straight to d_out)
// EPI 1: scatter bf16 -> Q,K as [B,H,N,DH]; V TRANSPOSED as [B,H,DH,NSEQ]
template <int EPI, int BM, int BN>
__global__ __launch_bounds__(256) void k_gemm_bt(const u16* __restrict__ A,
                                                 const u16* __restrict__ BT,
                                                 float* __restrict__ Of,
                                                 u16* __restrict__ O0,
                                                 u16* __restrict__ O1,
                                                 u16* __restrict__ O2) {
  constexpr int KD = 1024, BK = 64, NT = KD / BK;
  constexpr int MI = BM / 32, NI = BN / 32;   // frags per wave (2x2 grid)
  constexpr int AI = BM / 32, BI = BN / 32;   // staging instrs per wave
  __shared__ u16 As[BM * BK];
  __shared__ u16 Bs[BN * BK];
  const int m0 = blockIdx.x * BM, n0 = blockIdx.y * BN;
  const int t = threadIdx.x;
  const int w = t >> 6, l = t & 63, lo = l & 15, hi = l >> 4;
  const int wr = (w >> 1) * (BM / 2), wc = (w & 1) * (BN / 2);
  const int rl = l >> 3;
  const int sc8 = ((l & 7) ^ rl) * 8;
  const u16* agp[AI];
  u16* asd[AI];
#pragma unroll
  for (int i = 0; i < AI; i++) {
    const int ii = w * AI + i;
    agp[i] = A + (size_t)(m0 + ii * 8 + rl) * KD + sc8;
    asd[i] = (u16*)As + ii * 512;
  }
  const u16* bgp[BI];
  u16* bsd[BI];
#pragma unroll
  for (int i = 0; i < BI; i++) {
    const int ii = w * BI + i;
    bgp[i] = BT + (size_t)(n0 + ii * 8 + rl) * KD + sc8;
    bsd[i] = (u16*)Bs + ii * 512;
  }
  f32x4 acc[MI][NI] = {};

  for (int kt = 0; kt < NT; kt++) {
    const int k0 = kt * BK;
    __syncthreads();                   // prev tile's reads done
#pragma unroll
    for (int i = 0; i < AI; i++) GLDS(agp[i] + k0, asd[i]);
#pragma unroll
    for (int i = 0; i < BI; i++) GLDS(bgp[i] + k0, bsd[i]);
    __syncthreads();                   // drains vmcnt -> staged
    bf16x8 af[MI][2], bb[NI][2];
#pragma unroll
    for (int i = 0; i < MI; i++) {
      const int Ra = wr + i * 16 + lo, xa = Ra & 7;
      af[i][0] = ldbf8(&As[Ra * 64 + ((hi ^ xa) << 3)]);
      af[i][1] = ldbf8(&As[Ra * 64 + (((4 + hi) ^ xa) << 3)]);
    }
#pragma unroll
    for (int j = 0; j < NI; j++) {
      const int Rb = wc + j * 16 + lo, xb = Rb & 7;
      bb[j][0] = ldbf8(&Bs[Rb * 64 + ((hi ^ xb) << 3)]);
      bb[j][1] = ldbf8(&Bs[Rb * 64 + (((4 + hi) ^ xb) << 3)]);
    }
#pragma unroll
    for (int i = 0; i < MI; i++)
#pragma unroll
      for (int j = 0; j < NI; j++) {
        acc[i][j] = mfma16(af[i][0], bb[j][0], acc[i][j]);
        acc[i][j] = mfma16(af[i][1], bb[j][1], acc[i][j]);
      }
  }

#pragma unroll
  for (int i = 0; i < MI; i++) {
#pragma unroll
    for (int j = 0; j < NI; j++) {
      const int gr0 = m0 + wr + i * 16 + hi * 4;
      const int gc = n0 + wc + j * 16 + lo;
#pragma unroll
      for (int r = 0; r < 4; r++) {
        const int row = gr0 + r;
        if (EPI == 0) {
          Of[(size_t)row * 1024 + gc] = acc[i][j][r];   // fp32 output
        } else {
          const u16 bv = f2bf(acc[i][j][r]);
          const int which = gc >> 10, rem = gc & 1023;
          const int h = rem >> 6, dh = rem & 63;
          const int b = row >> 11, ns = row & 2047;
          if (which == 2) {   // V transposed: [B,H,DH,NSEQ]
            O2[(((size_t)b * NH + h) * NDH + dh) * NSEQ + ns] = bv;
          } else {
            const size_t idx = ((((size_t)b * NH + h) * NSEQ) + ns) * NDH + dh;
            (which == 0 ? O0 : O1)[idx] = bv;
          }
        }
      }
    }
  }
}

// ---------- rotary (interleaved pairs) on q (scaled) and k, fused ----------
__global__ __launch_bounds__(256) void k_rotary(u16* __restrict__ qb,
                                                u16* __restrict__ kb,
                                                const float* __restrict__ rot) {
  const int gi = blockIdx.x * 256 + threadIdx.x;   // 8-elem group id
  const int half = gi >> 19;                       // 2^19 groups per tensor
  const int i = gi & ((1 << 19) - 1);
  u16* buf = half ? kb : qb;
  const float scale = half ? 1.0f : 0.125f;        // q * DH^-0.5 folded in
  const int d0 = (i & 7) * 8;
  const int n = (i >> 3) & (NSEQ - 1);
  union { uint4 v; u16 s[8]; } u;
  u.v = *(const uint4*)(buf + (size_t)i * 8);
  float fr[8];
  *(float4*)&fr[0] = *(const float4*)(rot + n * NDH + d0);
  *(float4*)&fr[4] = *(const float4*)(rot + n * NDH + d0 + 4);
  union { uint4 v; u16 s[8]; } o;
#pragma unroll
  for (int p = 0; p < 4; p++) {
    float a = bf2f(u.s[2 * p]), b = bf2f(u.s[2 * p + 1]);
    float s0, c0, s1, c1;
    __sincosf(fr[2 * p], &s0, &c0);
    __sincosf(fr[2 * p + 1], &s1, &c1);
    o.s[2 * p] = f2bf((a * c0 - b * s0) * scale);
    o.s[2 * p + 1] = f2bf((b * c1 + a * s1) * scale);
  }
  *(uint4*)(buf + (size_t)i * 8) = o.v;
}

// ---------- flash attention: softcap, fixed-m softmax (m=0), causal --------
// p = exp(50*tanh(s/50)) via single exp2 + poly (log2e folded into consts).
// QBLK=64, 4-wave blocks: pairs (t,31-t) -> 33 uniform KV-tiles/block;
// grid 512 = 2 blocks/CU = 16 waves/CU. Async dbuf K/V staging via
// global_load_lds, ONE barrier per tile. (round-19 proven)
#define KCH(row, ch) ((((ch) ^ ((row) & 7)) * 8))
__global__ __launch_bounds__(256, 4) void k_attn(const u16* __restrict__ Q,
                                                 const u16* __restrict__ K,
                                                 const u16* __restrict__ Vt,
                                                 u16* __restrict__ O) {
  __shared__ u16 Ks[2][4096];       // [kv][dh] 16B-chunk XOR swizzled
  __shared__ u16 Vs[2][4096];       // [dh][kv] 16B-chunk XOR swizzled
  __shared__ u16 Ps[4][16][64];     // per-wave P [qrow][kv], XOR swizzled
  const int pr = blockIdx.x >> 5;          // 0..15 pair index
  const int bh = blockIdx.x & 31;
  const int b = bh >> 4, h = bh & 15;
  const size_t base = (size_t)bh * (NSEQ * NDH);
  const int t = threadIdx.x;
  const int w = t >> 6, l = t & 63, lo = l & 15, hi = l >> 4;

  const int rl = l >> 3;                  // row-in-chunk 0..7
  const int sc8 = ((l & 7) ^ rl) * 8;     // pre-swizzled chunk offset (elems)
  const size_t vtb = (size_t)bh * NDH * NSEQ;

#define STAGE(bb, kt_)                                                        \
  {                                                                           \
    _Pragma("unroll")                                                         \
    for (int i_ = 0; i_ < 2; i_++) {                                          \
      const int ii = w * 2 + i_;                                              \
      const int R_ = ii * 8 + rl;                                             \
      GLDS(K + base + (size_t)((kt_) * 64 + R_) * NDH + sc8,                  \
           &Ks[bb][ii * 512]);                                                \
      GLDS(Vt + vtb + (size_t)R_ * NSEQ + (kt_) * 64 + sc8,                   \
           &Vs[bb][ii * 512]);                                                \
    }                                                                         \
  }

  int cur = 0;
  STAGE(0, 0);                            // prologue: half0 tile0

#pragma unroll
  for (int half = 0; half < 2; half++) {
    const int qt = half ? (31 - pr) : pr;   // 64-row q tile
    const int q0 = qt * 64;
    bf16x8 aq0, aq1;
    {
      const u16* qp = Q + base + (size_t)(q0 + w * 16 + lo) * NDH;
      aq0 = ldbf8(qp + hi * 8);
      aq1 = ldbf8(qp + 32 + hi * 8);
    }
    f32x4 accO[4] = {};
    float l_part[4] = {0.f, 0.f, 0.f, 0.f};
    const int nkt = qt + 1;
    const int ktd = qt;                  // diagonal tile index
    const int rowg = q0 + w * 16 + hi * 4;

    for (int kt = 0; kt < nkt; kt++) {
      __syncthreads();   // drains vmcnt -> buf[cur] staged; prev reads done
      if (kt + 1 < nkt) {
        STAGE(cur ^ 1, kt + 1);          // flies over this tile's compute
      } else if (half == 0) {
        STAGE(cur ^ 1, 0);               // prefetch half1 tile0
      }

      // S = Q K^T
      const u16* ks = Ks[cur];
      const u16* vs = Vs[cur];
      f32x4 s[4];
#pragma unroll
      for (int nt = 0; nt < 4; nt++) {
        const int kr = nt * 16 + lo;
        f32x4 z = {};
        z = mfma16(aq0, ldbf8(&ks[kr * 64 + KCH(kr, hi)]), z);
        z = mfma16(aq1, ldbf8(&ks[kr * 64 + KCH(kr, 4 + hi)]), z);
        s[nt] = z;
      }
      // softcap+exp fused: p = 2^(v*(log2e - a2*z^2 + a4*z^4)), z=v/50
      const bool diag = (kt == ktd);
#pragma unroll
      for (int nt = 0; nt < 4; nt++) {
        const int col = kt * 64 + nt * 16 + lo;
#pragma unroll
        for (int r = 0; r < 4; r++) {
          const float v = s[nt][r];
          const float u = v * v;
          float p = fexp2(v * fmaf(u, fmaf(u, 3.0777855e-8f,
                                           -1.9235932e-4f), 1.44269504f));
          if (diag && col > rowg + r) p = 0.0f;
          s[nt][r] = p;
          l_part[r] += p;
        }
      }
      // P -> LDS (bf16), transpose C-layout -> A-frag layout (XOR swizzled)
#pragma unroll
      for (int nt = 0; nt < 4; nt++)
#pragma unroll
        for (int r = 0; r < 4; r++) {
          const int row = hi * 4 + r;
          Ps[w][row][KCH(row, 2 * nt + (lo >> 3)) + (lo & 7)] = f2bf(s[nt][r]);
        }

      const bf16x8 ap0 = ldbf8(&Ps[w][lo][KCH(lo, hi)]);
      const bf16x8 ap1 = ldbf8(&Ps[w][lo][KCH(lo, 4 + hi)]);
#pragma unroll
      for (int dt = 0; dt < 4; dt++) {
        const int d = dt * 16 + lo;
        accO[dt] = mfma16(ap0, ldbf8(&vs[d * 64 + KCH(d, hi)]), accO[dt]);
        accO[dt] = mfma16(ap1, ldbf8(&vs[d * 64 + KCH(d, 4 + hi)]), accO[dt]);
      }
      cur ^= 1;
    }
    // epilogue: reduce l across the 16 lo-lanes, normalize, write [B,N,H*DH]
    float lr[4];
#pragma unroll
    for (int r = 0; r < 4; r++) {
      float lv = l_part[r];
      lv += __shfl_xor(lv, 1, 64);
      lv += __shfl_xor(lv, 2, 64);
      lv += __shfl_xor(lv, 4, 64);
      lv += __shfl_xor(lv, 8, 64);
      lr[r] = __builtin_amdgcn_rcpf(lv);
    }
#pragma unroll
    for (int dt = 0; dt < 4; dt++) {
#pragma unroll
      for (int r = 0; r < 4; r++) {
        const int row = rowg + r;
        const float v = accO[dt][r] * lr[r];
        const size_t idx = (((size_t)(b * NSEQ + row)) * NH + h) * NDH + dt * 16 + lo;
        O[idx] = f2bf(v);
      }
    }
  }
#undef STAGE
}

extern "C" void kernel_launch(void* const* d_in, const int* in_sizes, int n_in,
                              void* d_out, int out_size, void* d_ws, size_t ws_size,
                              hipStream_t stream) {
  const float* x     = (const float*)d_in[0];
  // d_in[1] = attn_mask (bool causal tril) -- implemented directly
  const float* rot   = (const float*)d_in[2];
  const float* gamma = (const float*)d_in[3];
  const float* wqkv  = (const float*)d_in[4];
  const float* wout  = (const float*)d_in[5];

  char* ws = (char*)d_ws;
  u16* xn    = (u16*)(ws);                        // 8 MB, reused as attn-out
  u16* wqkvT = (u16*)(ws + (size_t)( 8u << 20));  // 6 MB
  u16* woutT = (u16*)(ws + (size_t)(14u << 20));  // 2 MB
  u16* qb    = (u16*)(ws + (size_t)(16u << 20));  // 8 MB
  u16* kb    = (u16*)(ws + (size_t)(24u << 20));  // 8 MB
  u16* vt    = (u16*)(ws + (size_t)(32u << 20));  // 8 MB  [B,H,DH,NSEQ]
  u16* ob    = xn;                                 // xn dead after QKV GEMM

  k_transpose<<<dim3(16, 48), 256, 0, stream>>>(wqkv, wqkvT, 1024, 3072);
  k_transpose<<<dim3(16, 16), 256, 0, stream>>>(wout, woutT, 1024, 1024);
  k_rmsnorm<<<4096, 256, 0, stream>>>(x, gamma, xn);
  k_gemm_bt<1, 64, 128><<<dim3(64, 24), 256, 0, stream>>>(
      xn, wqkvT, nullptr, qb, kb, vt);
  k_rotary<<<4096, 256, 0, stream>>>(qb, kb, rot);
  k_attn<<<512, 256, 0, stream>>>(qb, kb, vt, ob);
  k_gemm_bt<0, 64, 64><<<dim3(64, 16), 256, 0, stream>>>(
      ob, woutT, (float*)d_out, nullptr, nullptr, nullptr);
}